// Round 6
// baseline (590.411 us; speedup 1.0000x reference)
//
#include <hip/hip_runtime.h>
#include <hip/hip_bf16.h>
#include <math.h>

#define BB 128
#define LL 4096
#define ROWB 256            // bytes per activation row (128 bf16)
#define LP3 4072            // valid rows after 3 VALID convs
#define TROWS 168           // LDS tile rows (128 out + 24 halo + clamp pad)
#define XB (TROWS*ROWB)     // 43008
#define EOFF XB             // emb table bf16 (1024 B)
#define TOFF (EOFF + 1024)  // tokens (168*4 B)
#define LDSSZ (TOFF + 672)  // 44704 -> 3 blocks/CU
#define REDOFF 33024        // mean-reduction scratch inside X rows 129..161
#define NSTEP 216           // 3 layers x 72 K16-steps
#define WELEM (NSTEP*2048)  // 442368 weight elements (4 KB/step)

typedef __bf16 bf16;
typedef __bf16 bf16x8 __attribute__((ext_vector_type(8)));
typedef float  f32x16 __attribute__((ext_vector_type(16)));

#define MFMA32(va,vb,vc) __builtin_amdgcn_mfma_f32_32x32x16_bf16(va,vb,vc,0,0,0)

__device__ __forceinline__ float bf2f(unsigned int u){
  union{unsigned int i; float f;} c; c.i = (u & 0xffffu) << 16; return c.f;
}
__device__ __forceinline__ unsigned short f2bfbits(float f){
  union { bf16 h; unsigned short s; } u; u.h = (bf16)f; return u.s;
}
__device__ __forceinline__ void acc8(float* a, uint4 v, float s){
  a[0] += s*bf2f(v.x); a[1] += s*bf2f(v.x>>16);
  a[2] += s*bf2f(v.y); a[3] += s*bf2f(v.y>>16);
  a[4] += s*bf2f(v.z); a[5] += s*bf2f(v.z>>16);
  a[6] += s*bf2f(v.w); a[7] += s*bf2f(v.w>>16);
}

// ---- weight re-layout for 32x32x16. Step s = layer*72 + tap*8 + kc8 (4 KB).
// Within step (elements): idx2 = b32*512 + kh*256 + row*8 + j
//   cout = b32*32 + row ; cin = kc8*16 + kh*8 + j
// -> wave A frag (b32) = 1024 contiguous bytes, lane l reads 16B at
//    (l>>5)*512 + (l&31)*16: A[m=l&31][k=(l>>5)*8+j].
__global__ void k_prep_w(const float* __restrict__ w1, const float* __restrict__ wr,
                         bf16* __restrict__ wg){
  int idx = blockIdx.x*256 + threadIdx.x;
  if (idx >= WELEM) return;
  int s    = idx >> 11;
  int r11  = idx & 2047;
  int b32  = r11 >> 9;
  int kh   = (r11 >> 8) & 1;
  int row  = (r11 >> 3) & 31;
  int j    = idx & 7;
  int layer = s / 72;
  int w72   = s - layer*72;
  int tap = w72 >> 3, kc8 = w72 & 7;
  int cout = b32*32 + row;
  int cin  = kc8*16 + kh*8 + j;
  float w = (layer==0) ? w1[(cout*128+cin)*9 + tap]
                       : wr[(((layer-1)*128 + cout)*128 + cin)*9 + tap];
  wg[idx] = (bf16)w;
}

// A fragments (2 per wave) for step tt: 2 coalesced 16B global loads (L1-resident)
#define GLOADA(P0,P1,tt) do{                                             \
  const char* p_ = wA + (size_t)(tt)*4096;                               \
  P0 = *(const bf16x8*)(p_);                                             \
  P1 = *(const bf16x8*)(p_+1024);                                        \
}while(0)

// B fragments for K16-step kss from swizzled X rows (frag stride 32 rows = 8 KB)
#define PRELOADB(B0,B1,B2,kss) do{                                       \
  const int tap_ = (kss)>>3;                                             \
  const int ch_ = ((((((kss)&7)<<1)+h) ^ ((r31+tap_)&7)) << 4);          \
  const char* bp_ = bBase + tap_*256 + ch_;                              \
  B0 = *(const bf16x8*)(bp_);                                            \
  if (nf2) B1 = *(const bf16x8*)(bp_+8192);                              \
  if (nf3) B2 = *(const bf16x8*)(bp_+16384);                             \
}while(0)

#define DOMFMA(A0,A1,B0,B1,B2) do{                                       \
  __builtin_amdgcn_s_setprio(1);                                         \
  acc[0][0]=MFMA32(A0,B0,acc[0][0]); acc[1][0]=MFMA32(A1,B0,acc[1][0]);  \
  if (nf2){ acc[0][1]=MFMA32(A0,B1,acc[0][1]);                           \
            acc[1][1]=MFMA32(A1,B1,acc[1][1]); }                         \
  if (nf3){ acc[0][2]=MFMA32(A0,B2,acc[0][2]);                           \
            acc[1][2]=MFMA32(A1,B2,acc[1][2]); }                         \
  __builtin_amdgcn_s_setprio(0);                                         \
}while(0)

#define ZERO16 {0.f,0.f,0.f,0.f,0.f,0.f,0.f,0.f,0.f,0.f,0.f,0.f,0.f,0.f,0.f,0.f}

// ---- fused embed + 3 convs + mean partials; barrier-free K-loop, 32x32 MFMA ----
__global__ __launch_bounds__(256, 3)
void k_fused(const int* __restrict__ tokens, const float* __restrict__ emb,
             const bf16* __restrict__ wg, const float* __restrict__ b1,
             const float* __restrict__ br, bf16* __restrict__ x3,
             float* __restrict__ meanv){
  __shared__ __align__(16) char lds[LDSSZ];
  const int tid  = threadIdx.x;
  const int lane = tid & 63;
  const int w    = tid >> 6;
  const int wm   = w >> 1, wn = w & 1;
  const int b    = blockIdx.x >> 5;
  const int l0   = (blockIdx.x & 31) << 7;
  const int r31  = lane & 31, h = lane >> 5;
  const char* wbytes = (const char*)wg;
  const char* wA = wbytes + (wm<<11) + (r31<<4) + (h<<9);
  const int rowbase = 96*wn;
  const char* bBase = lds + (rowbase + r31)*256;

  int*  Tk = (int*)(lds + TOFF);
  bf16* Eb = (bf16*)(lds + EOFF);
  if (tid < TROWS){
    int l = l0 + tid; if (l > LL-1) l = LL-1;   // clamped halo (rows masked later)
    Tk[tid] = tokens[b*LL + l];
  }
  Eb[tid]     = (bf16)emb[tid];
  Eb[tid+256] = (bf16)emb[tid+256];
  __syncthreads();
  for (int t2 = tid; t2 < TROWS*16; t2 += 256){
    int s = t2 >> 4, c16 = t2 & 15;
    bf16x8 v = *(const bf16x8*)((const char*)Eb + Tk[s]*256 + c16*16);
    *(bf16x8*)(lds + s*ROWB + ((c16 ^ (s&7))<<4)) = v;
  }
  __syncthreads();

  for (int layer = 0; layer < 3; ++layer){
    const int layer72 = layer*72;
    const bool nf3 = (wn == 0);
    const bool nf2 = nf3 || (layer < 2);
    f32x16 acc[2][3];
    acc[0][0]=(f32x16)ZERO16; acc[1][0]=(f32x16)ZERO16;
    acc[0][1]=(f32x16)ZERO16; acc[1][1]=(f32x16)ZERO16;
    acc[0][2]=(f32x16)ZERO16; acc[1][2]=(f32x16)ZERO16;

    bf16x8 P0,P1,Q0,Q1;
    bf16x8 B0,B1,B2,D0,D1,D2;
    GLOADA(P0,P1, layer72);
    GLOADA(Q0,Q1, layer72+1);
    PRELOADB(B0,B1,B2, 0);

    #pragma unroll 1
    for (int it = 0; it < 36; ++it){
      const int ks = it << 1;
      const int t  = layer72 + ks;
      PRELOADB(D0,D1,D2, ks+1);
      DOMFMA(P0,P1, B0,B1,B2);
      GLOADA(P0,P1, t+2);                  // WAR on P keeps this after MFMA
      if (ks < 70) PRELOADB(B0,B1,B2, ks+2);
      DOMFMA(Q0,Q1, D0,D1,D2);
      GLOADA(Q0,Q1, t+3);                  // blob padded +3 steps: always valid
    }
    __syncthreads();                        // all reads of X(layer) done

    // epilogue: +bias, pack bf16, write in place.
    // 32x32 C/D map: n = rowpos = lane&31; cout = (reg&3) + 8*(reg>>2) + 4*h.
    const float* bias = (layer == 0) ? b1 : (br + (layer-1)*128);
    #pragma unroll
    for (int mf=0; mf<2; mf++){
      const int mfbase = wm*64 + mf*32;
      #pragma unroll
      for (int nf=0; nf<3; nf++){
        bool on = (nf==0) | (nf==1 && nf2) | (nf==2 && nf3);
        if (on){
          int nn = rowbase + nf*32 + r31;
          f32x16 v = acc[mf][nf];
          #pragma unroll
          for (int q=0; q<4; q++){
            int cbase = mfbase + 8*q + 4*h;
            float4 bvx = *(const float4*)(bias + cbase);
            ushort4 pk;
            pk.x = f2bfbits(v[4*q+0] + bvx.x);
            pk.y = f2bfbits(v[4*q+1] + bvx.y);
            pk.z = f2bfbits(v[4*q+2] + bvx.z);
            pk.w = f2bfbits(v[4*q+3] + bvx.w);
            int chunk = cbase >> 3;
            *(ushort4*)(lds + nn*ROWB + ((chunk ^ (nn&7))<<4) + ((cbase&7)<<1)) = pk;
          }
        }
      }
    }
    __syncthreads();                        // writes visible before next layer
  }

  // store rows 0..127 (swizzled image identical in LDS and global)
  char* dst = (char*)x3 + ((size_t)b*LL + l0)*ROWB;
  #pragma unroll
  for (int p=0;p<8;p++){
    int off = p*4096 + tid*16;
    int row = off >> 8;
    if (l0 + row < LP3)
      *(uint4*)(dst + off) = *(const uint4*)(lds + off);
  }
  // mean partials: column sums of this tile -> atomicAdd (meanv pre-zeroed)
  {
    int lc = tid & 15, rg = tid >> 4;
    float am[8] = {0,0,0,0,0,0,0,0};
    for (int l = rg; l < 128; l += 16){
      if (l0 + l < LP3){
        uint4 v = *(const uint4*)(lds + l*ROWB + ((lc ^ (l&7))<<4));
        acc8(am, v, 1.0f);
      }
    }
    float* red = (float*)(lds + REDOFF);    // rows 129..161: not read below
    __syncthreads();
    #pragma unroll
    for (int j=0;j<8;j++) red[tid*8+j] = am[j];
    __syncthreads();
    if (tid < 128){
      int lc2 = tid >> 3, j = tid & 7;
      float s = 0.f;
      for (int rg2=0; rg2<16; rg2++) s += red[(rg2*16+lc2)*8 + j];
      atomicAdd(&meanv[b*128 + tid], s);
    }
  }
}

// ---- q = Wq.(mean) + bq ; qk = Wk^T q (scaled) ; cb = q.bk (scaled) ----
__global__ void k_qk(const float* __restrict__ meanv, const float* __restrict__ wq,
                     const float* __restrict__ bq, const float* __restrict__ wk,
                     const float* __restrict__ bk, float* __restrict__ qk,
                     float* __restrict__ cbv){
  __shared__ float mv[128], qv[128];
  int b = blockIdx.x, i = threadIdx.x;
  mv[i] = meanv[b*128+i] * (1.0f/LP3);
  __syncthreads();
  float q = bq[i];
  for (int j=0;j<128;j++) q += wq[i*128+j]*mv[j];
  qv[i] = q;
  __syncthreads();
  const float scale = 0.088388347648318447f; // 1/sqrt(128)
  float s = 0.f;
  for (int d=0; d<128; d++) s += qv[d]*wk[d*128+i];
  qk[b*128+i] = s*scale;
  if (i==0){
    float c = 0.f;
    for (int d=0; d<128; d++) c += qv[d]*bk[d];
    cbv[b] = c*scale;
  }
}

// ---- fused scores + weighted sum: one pass over x3 ----
__global__ __launch_bounds__(256)
void k_attn(const bf16* __restrict__ x3, const float* __restrict__ qk,
            const float* __restrict__ cbv, float* __restrict__ xa,
            float* __restrict__ sums){
  __shared__ float qks[128];
  __shared__ float red[2048];
  __shared__ float wsm[4];
  int b = blockIdx.x >> 2, seg = blockIdx.x & 3;
  int tid = threadIdx.x;
  int lc = tid & 15, rg = tid >> 4;
  if (tid < 128) qks[tid] = qk[b*128 + tid];
  __syncthreads();
  float cb = cbv[b];
  const char* base = (const char*)x3 + (size_t)b*LL*ROWB;
  const float* qp = qks + lc*8;
  float a[8] = {0,0,0,0,0,0,0,0};
  float esum = 0.f;
  for (int it=0; it<64; it++){
    int l = seg*1024 + it*16 + rg;
    uint4 v = *(const uint4*)(base + l*ROWB + ((lc ^ (l&7))<<4));
    float p = bf2f(v.x)*qp[0] + bf2f(v.x>>16)*qp[1]
            + bf2f(v.y)*qp[2] + bf2f(v.y>>16)*qp[3]
            + bf2f(v.z)*qp[4] + bf2f(v.z>>16)*qp[5]
            + bf2f(v.w)*qp[6] + bf2f(v.w>>16)*qp[7];
    p += __shfl_xor(p, 1); p += __shfl_xor(p, 2);
    p += __shfl_xor(p, 4); p += __shfl_xor(p, 8);
    if (l < LP3){
      float e = __expf(p + cb);
      esum += e;
      acc8(a, v, e);
    }
  }
  #pragma unroll
  for (int j=0;j<8;j++) red[tid*8+j] = a[j];
  esum += __shfl_xor(esum, 16);
  esum += __shfl_xor(esum, 32);
  if ((tid & 63) == 0) wsm[tid>>6] = esum;
  __syncthreads();
  if (tid < 128){
    int lc2 = tid >> 3, j = tid & 7;
    float s = 0.f;
    for (int rg2=0; rg2<16; rg2++) s += red[(rg2*16+lc2)*8 + j];
    atomicAdd(&xa[b*128 + tid], s);
  }
  if (tid == 0) atomicAdd(&sums[b], wsm[0]+wsm[1]+wsm[2]+wsm[3]);
}

// ---- out = Wv.(xa/sum) + bv ----
__global__ void k_out(const float* __restrict__ xa, const float* __restrict__ sums,
                      const float* __restrict__ wv, const float* __restrict__ bv,
                      float* __restrict__ out){
  __shared__ float xs[128];
  int b = blockIdx.x, i = threadIdx.x;
  xs[i] = xa[b*128+i] / sums[b];
  __syncthreads();
  float o = bv[i];
  for (int j=0;j<128;j++) o += wv[i*128+j]*xs[j];
  out[b*128+i] = o;
}

extern "C" void kernel_launch(void* const* d_in, const int* in_sizes, int n_in,
                              void* d_out, int out_size, void* d_ws, size_t ws_size,
                              hipStream_t stream){
  const int*   tokens = (const int*)d_in[0];
  const float* emb    = (const float*)d_in[1];
  const float* w1     = (const float*)d_in[2];
  const float* b1     = (const float*)d_in[3];
  const float* wr     = (const float*)d_in[4];
  const float* br     = (const float*)d_in[5];
  const float* wqw    = (const float*)d_in[6];
  const float* wqb    = (const float*)d_in[7];
  const float* wkw    = (const float*)d_in[8];
  const float* wkb    = (const float*)d_in[9];
  const float* wvw    = (const float*)d_in[10];
  const float* wvb    = (const float*)d_in[11];
  float* out = (float*)d_out;

  const size_t X3SZ  = (size_t)BB*LL*ROWB;           // 134217728
  const size_t WGSZ  = (size_t)(NSTEP+3)*4096;       // 897024 (3 pad steps)
  const size_t AUXSZ = 204800;
  const size_t NEED  = X3SZ + WGSZ + AUXSZ;
  if (ws_size < NEED){
    hipMemsetAsync(d_out, 0, (size_t)out_size*4, stream);
    return;
  }
  char* ws = (char*)d_ws;
  bf16*  x3    = (bf16*)ws;
  bf16*  wg    = (bf16*)(ws + X3SZ);
  char*  aux   = ws + X3SZ + WGSZ;
  float* meanv = (float*)aux;
  float* xabuf = (float*)(aux + 65536);
  float* sums  = (float*)(aux + 131072);
  float* qkbuf = (float*)(aux + 135168);
  float* cbbuf = (float*)(aux + 200704);

  hipMemsetAsync(aux, 0, 135168, stream);            // meanv + xa + sums
  k_prep_w<<<1728, 256, 0, stream>>>(w1, wr, wg);
  k_fused<<<4096, 256, 0, stream>>>(tokens, emb, wg, b1, br, x3, meanv);
  k_qk<<<128, 128, 0, stream>>>(meanv, wqw, wqb, wkw, wkb, qkbuf, cbbuf);
  k_attn<<<512, 256, 0, stream>>>(x3, qkbuf, cbbuf, xabuf, sums);
  k_out<<<128, 128, 0, stream>>>(xabuf, sums, wvw, wvb, out);
}